// Round 22
// baseline (91.961 us; speedup 1.0000x reference)
//
#include <hip/hip_runtime.h>
#include <hip/hip_bf16.h>
#include <math.h>

// Problem constants (from setup_inputs / reference)
#define CLASSES     5
#define C_DIM       64
#define HW          441            // 21*21
#define B_ANCH      32
#define NSUP        25             // L*S support images
#define NROWS       (B_ANCH*HW)    // 14112 query rows
#define MSUP        (NSUP*HW)      // 11025 support descriptors
#define PER_CLS     (MSUP/CLASSES) // 2205 per class
#define TILE_COLS   32
#define ROW_BYTES   (C_DIM*2)      // 128 B per bf16 descriptor row
#define TILE_BYTES  (TILE_COLS*ROW_BYTES)   // 4 KB
#define PER_CLS_PAD 2304           // 72 tiles of 32
#define NPAD        (PER_CLS_PAD - PER_CLS) // 99 zero-filled pad rows/class
#define QUARTERS    4              // column splits per class (grid.y = 5*4)
#define TILES_PER_Q 18             // 18 tiles of 32 cols = 576 cols/quarter
#define ROWS_PER_BLK 128           // 4 waves x 32 query rows
#define NBLK_X      ((NROWS + ROWS_PER_BLK - 1) / ROWS_PER_BLK)  // 111

#define NEG_INF  (-1e30f)

typedef __bf16 bf16x8 __attribute__((ext_vector_type(8)));
typedef float  f32x4  __attribute__((ext_vector_type(4)));

// top-3 insert via med3: 3 independent ops; t0 >= t1 >= t2 invariant.
#define TOP3_INS(v, t0, t1, t2) do {                              \
    float _v = (v);                                               \
    float _n0 = fmaxf(_v, (t0));                                  \
    float _n1 = __builtin_amdgcn_fmed3f(_v, (t0), (t1));          \
    float _n2 = __builtin_amdgcn_fmed3f(_v, (t1), (t2));          \
    (t0) = _n0; (t1) = _n1; (t2) = _n2; } while (0)

// Merge two SORTED triples (u desc, v desc) -> u = top-3 of union. 6 ops.
// Field-validated rounds 9-21 (absmax 0).
#define TRIPLE_MERGE(u0, u1, u2, v0, v1, v2) do {                 \
    float _A = fminf((u0), (v0));                                 \
    float _B = fmaxf((u1), (v1));                                 \
    float _E = fmaxf((u2), (v2));                                 \
    float _m0 = fmaxf((u0), (v0));                                \
    float _m1 = __builtin_amdgcn_fmed3f((u0), (v0), _B);          \
    float _m2 = __builtin_amdgcn_fmed3f(_A, _B, _E);              \
    (u0) = _m0; (u1) = _m1; (u2) = _m2; } while (0)

#define MFMA16(A, B, C) __builtin_amdgcn_mfma_f32_16x16x32_bf16((A), (B), (C), 0, 0, 0)

// ---------------------------------------------------------------------------
// Kernel 1: L2-normalize all rows (support + anchor) into row-major bf16.
// Support -> sb with per-class row stride PER_CLS_PAD; pad rows zero-filled.
// ---------------------------------------------------------------------------
__global__ __launch_bounds__(256) void norm_rows_kernel(
    const float* __restrict__ anchor, const float* __restrict__ support,
    __bf16* __restrict__ qb, __bf16* __restrict__ sb) {
    int r = blockIdx.x * 256 + threadIdx.x;
    const int total_main = MSUP + NROWS;
    if (r >= total_main) {
        int i = r - total_main;                    // pad-row zero fill
        if (i < CLASSES * NPAD) {
            int cls = i / NPAD, ix = PER_CLS + i % NPAD;
            __bf16* op = sb + ((size_t)cls * PER_CLS_PAD + ix) * C_DIM;
            bf16x8 z = {};
            #pragma unroll
            for (int c0 = 0; c0 < C_DIM; c0 += 8) *(bf16x8*)(op + c0) = z;
        }
        return;
    }
    bool isSup = r < MSUP;
    int rc = isSup ? r : r - MSUP;
    const float* in = isSup ? support : anchor;
    int img = rc / HW, p = rc % HW;
    const float* base = in + (size_t)img * C_DIM * HW + p;
    float q[C_DIM];
    float ss = 0.f;
    #pragma unroll
    for (int c = 0; c < C_DIM; ++c) { q[c] = base[c * HW]; ss += q[c] * q[c]; }
    float sc = rsqrtf(ss);
    __bf16* op;
    if (isSup) {
        int cls = rc / PER_CLS, ix = rc - cls * PER_CLS;
        op = sb + ((size_t)cls * PER_CLS_PAD + ix) * C_DIM;
    } else {
        op = qb + (size_t)rc * C_DIM;
    }
    #pragma unroll
    for (int c0 = 0; c0 < C_DIM; c0 += 8) {
        bf16x8 v;
        #pragma unroll
        for (int j = 0; j < 8; ++j) v[j] = (__bf16)(q[c0 + j] * sc);
        *(bf16x8*)(op + c0) = v;
    }
}

// ---------------------------------------------------------------------------
// L1-DIRECT, SWAPPED-OPERAND GEMM+top3 over one column-quarter.
// R20's math with zero LDS / zero barriers: support A-fragments are loaded
// DIRECTLY global->VGPR. All 4 waves of a block read IDENTICAL addresses
// (the per-wave state is only the query registers), so the 4 KB tile is
// L1-resident and 3 of 4 waves hit L1 — this is R9's idea without its
// 4-independent-streams L1 thrash. Waves fully self-paced; 3-deep named
// register pipeline (A/B/C, compile-time t%3 under full unroll); the
// compiler emits counted vmcnt for the register loads automatically.
// TAIL: s=1 support row = 2192+kg*4+j, valid iff (j==0)||(kg<3).
// ---------------------------------------------------------------------------
template<int QNT, bool TAIL>
__device__ __forceinline__ void scan_quarter(
    const char* abase,            // per-lane: qbase + lr*128 + kg*16
    int kg,
    const bf16x8 qh0[2], const bf16x8 qh1[2],
    float u0[2], float u1[2], float u2[2]) {

    bf16x8 A[4], B[4], C[4];      // 3 tile slots; constant indices only
    auto load = [&](bf16x8 d[4], int t) {
        const char* p = abase + t * TILE_BYTES;
        d[0] = *(const bf16x8*)(p);               // s=0, k-half 0
        d[1] = *(const bf16x8*)(p + 64);          // s=0, k-half 1
        d[2] = *(const bf16x8*)(p + 2048);        // s=1, k-half 0
        d[3] = *(const bf16x8*)(p + 2048 + 64);   // s=1, k-half 1
    };
    const f32x4 z = {0.f, 0.f, 0.f, 0.f};

    auto comp = [&](const bf16x8 s[4], int t) {
        f32x4 acc00, acc01, acc10, acc11;
        __builtin_amdgcn_s_setprio(1);
        acc00 = MFMA16(s[0], qh0[0], z); acc00 = MFMA16(s[1], qh1[0], acc00);
        acc01 = MFMA16(s[0], qh0[1], z); acc01 = MFMA16(s[1], qh1[1], acc01);
        acc10 = MFMA16(s[2], qh0[0], z); acc10 = MFMA16(s[3], qh1[0], acc10);
        acc11 = MFMA16(s[2], qh0[1], z); acc11 = MFMA16(s[3], qh1[1], acc11);
        __builtin_amdgcn_s_setprio(0);
        const bool tail = TAIL && (t == QNT - 1);
        if (!tail) {
            #pragma unroll
            for (int j = 0; j < 4; ++j) {
                TOP3_INS(acc00[j], u0[0], u1[0], u2[0]);
                TOP3_INS(acc01[j], u0[1], u1[1], u2[1]);
                TOP3_INS(acc10[j], u0[0], u1[0], u2[0]);
                TOP3_INS(acc11[j], u0[1], u1[1], u2[1]);
            }
        } else {
            // s=0 rows (2176..2191) all valid; s=1 row = 2192+kg*4+j,
            // valid iff kg*4+j < 13  <=>  (j==0) || (kg<3)
            #pragma unroll
            for (int j = 0; j < 4; ++j) {
                TOP3_INS(acc00[j], u0[0], u1[0], u2[0]);
                TOP3_INS(acc01[j], u0[1], u1[1], u2[1]);
                bool validj = (j == 0) || (kg < 3);
                float v0 = validj ? acc10[j] : NEG_INF;
                float v1 = validj ? acc11[j] : NEG_INF;
                TOP3_INS(v0, u0[0], u1[0], u2[0]);
                TOP3_INS(v1, u0[1], u1[1], u2[1]);
            }
        }
    };

    load(A, 0);
    load(B, 1);
    #pragma unroll
    for (int t = 0; t < QNT; ++t) {
        switch (t % 3) {                           // compile-time under unroll
            case 0:  if (t + 2 < QNT) load(C, t + 2); comp(A, t); break;
            case 1:  if (t + 2 < QNT) load(A, t + 2); comp(B, t); break;
            default: if (t + 2 < QNT) load(B, t + 2); comp(C, t); break;
        }
    }
}

// ---------------------------------------------------------------------------
// Kernel 2: MFMA GEMM + partial top-3 per (row, class, quarter).
// Grid (111, 20), block 256 = 4 fully self-paced waves; wave owns 32 rows.
// NO LDS, NO barriers. A-frag (support, global/L1): row = lane&15,
// k = (lane>>4)*8+[0..7]. B-frag (query, regs): col = lane&15, same k.
// C/D: col(query) = lane&15, row(support) = (lane>>4)*4 + reg.
// part layout: [cls][row][quarter][3] (coalesced merge reads).
// ---------------------------------------------------------------------------
__global__ __launch_bounds__(256, 4) void knn_mfma_kernel(
    const __bf16* __restrict__ qb, const __bf16* __restrict__ sb,
    float* __restrict__ part) {
    int lane = threadIdx.x & 63;
    int w    = threadIdx.x >> 6;           // 0..3
    int lr   = lane & 15;
    int kg   = lane >> 4;
    int cls  = blockIdx.y >> 2;
    int q    = blockIdx.y & 3;
    int rowbase = blockIdx.x * ROWS_PER_BLK + w * 32;

    // query B-frags for the wave's two 16-row groups (clamped ragged tail)
    bf16x8 qh0[2], qh1[2];
    #pragma unroll
    for (int f = 0; f < 2; ++f) {
        int r = rowbase + f * 16 + lr;
        r = r < NROWS ? r : NROWS - 1;
        const bf16x8* qr = (const bf16x8*)(qb + (size_t)r * C_DIM);
        qh0[f] = qr[kg];
        qh1[f] = qr[4 + kg];
    }

    float u0[2], u1[2], u2[2];
    #pragma unroll
    for (int f = 0; f < 2; ++f) { u0[f] = NEG_INF; u1[f] = NEG_INF; u2[f] = NEG_INF; }

    // per-lane A-fragment base: support row lr of the tile, k-offset kg*16
    const char* abase = (const char*)sb
        + (size_t)cls * PER_CLS_PAD * ROW_BYTES
        + (size_t)q * TILES_PER_Q * TILE_BYTES
        + lr * ROW_BYTES + kg * 16;

    if (q == 3)   // tiles 54..68 valid (69..71 all-pad skipped), tail masked
        scan_quarter<15, true >(abase, kg, qh0, qh1, u0, u1, u2);
    else
        scan_quarter<18, false>(abase, kg, qh0, qh1, u0, u1, u2);

    // Merge top-3 across the 4 kg-lanes per query row (offsets 16, 32);
    // 2 chains x 2 steps x 3 shfl = 12 shuffles/wave.
    #pragma unroll
    for (int f = 0; f < 2; ++f) {
        float a0 = u0[f], a1 = u1[f], a2 = u2[f];
        #pragma unroll
        for (int off = 16; off < 64; off <<= 1) {
            float v0 = __shfl_xor(a0, off, 64);
            float v1 = __shfl_xor(a1, off, 64);
            float v2 = __shfl_xor(a2, off, 64);
            TRIPLE_MERGE(a0, a1, a2, v0, v1, v2);
        }
        int row = rowbase + f * 16 + lr;
        if (kg == 0 && row < NROWS) {
            float* pp = part +
                (((size_t)cls * NROWS + row) * QUARTERS + q) * 3;
            pp[0] = a0; pp[1] = a1; pp[2] = a2;
        }
    }
}

// ---------------------------------------------------------------------------
// Kernel 3: merge quarter partial top-3s, sigmoid, reduce over 441 locations.
// part layout [cls][row][q][3]: lane-adjacent rows are 48B apart -> coalesced.
// ---------------------------------------------------------------------------
__global__ __launch_bounds__(64) void merge_reduce_kernel(
    const float* __restrict__ part, float* __restrict__ out) {
    int bl = blockIdx.x;
    int b = bl / CLASSES;
    int l = bl % CLASSES;
    int lane = threadIdx.x;
    float acc = 0.f;
    for (int p = lane; p < HW; p += 64) {
        int row = b * HW + p;
        const float* pp = part + (((size_t)l * NROWS + row) * QUARTERS) * 3;
        float u0 = pp[0], u1 = pp[1], u2 = pp[2];
        TRIPLE_MERGE(u0, u1, u2, pp[3], pp[4],  pp[5]);
        TRIPLE_MERGE(u0, u1, u2, pp[6], pp[7],  pp[8]);
        TRIPLE_MERGE(u0, u1, u2, pp[9], pp[10], pp[11]);
        acc += 1.f / (1.f + __expf(-u0))
             + 1.f / (1.f + __expf(-u1))
             + 1.f / (1.f + __expf(-u2));
    }
    #pragma unroll
    for (int off = 32; off; off >>= 1) acc += __shfl_xor(acc, off, 64);
    if (lane == 0) out[bl] = acc;
}

// ---------------------------------------------------------------------------
extern "C" void kernel_launch(void* const* d_in, const int* in_sizes, int n_in,
                              void* d_out, int out_size, void* d_ws, size_t ws_size,
                              hipStream_t stream) {
    const float* anchor  = (const float*)d_in[0];
    const float* support = (const float*)d_in[1];
    // d_in[2]=av_num(1), d_in[3]=sav_num(1) -- fixed by setup, ignored.

    // ws: sb bf16[5*2304*64] | qb bf16[NROWS*64] | part f32[5*NROWS*4*3]
    __bf16* sb = (__bf16*)d_ws;
    __bf16* qb = sb + (size_t)CLASSES * PER_CLS_PAD * C_DIM;
    float* part = (float*)(qb + (size_t)NROWS * C_DIM);

    {
        int total = MSUP + NROWS + CLASSES * NPAD;
        dim3 g((total + 255) / 256);
        norm_rows_kernel<<<g, 256, 0, stream>>>(anchor, support, qb, sb);
    }
    {
        dim3 g(NBLK_X, CLASSES * QUARTERS);
        knn_mfma_kernel<<<g, 256, 0, stream>>>(qb, sb, part);
    }
    {
        dim3 gm(B_ANCH * CLASSES);
        merge_reduce_kernel<<<gm, 64, 0, stream>>>(part, (float*)d_out);
    }
}

// Round 23
// 47.608 us; speedup vs baseline: 1.9316x; 1.9316x over previous
//
#include <hip/hip_runtime.h>
#include <hip/hip_bf16.h>
#include <math.h>

// Problem constants (from setup_inputs / reference)
#define CLASSES     5
#define C_DIM       64
#define HW          441            // 21*21
#define B_ANCH      32
#define NSUP        25             // L*S support images
#define NROWS       (B_ANCH*HW)    // 14112 query rows
#define MSUP        (NSUP*HW)      // 11025 support descriptors
#define PER_CLS     (MSUP/CLASSES) // 2205 per class
#define TILE_COLS   32
#define ROW_BYTES   (C_DIM*2)      // 128 B per bf16 descriptor row
#define TILE_BYTES  (TILE_COLS*ROW_BYTES)   // 4 KB
#define PER_CLS_PAD 2304           // 72 tiles of 32
#define NPAD        (PER_CLS_PAD - PER_CLS) // 99 zero-filled pad rows/class
#define QUARTERS    4              // column splits per class (grid.y = 5*4)
#define TILES_PER_Q 18             // 18 tiles of 32 cols = 576 cols/quarter
#define ROWS_PER_BLK 128           // 4 waves x 32 query rows
#define NBLK_X      ((NROWS + ROWS_PER_BLK - 1) / ROWS_PER_BLK)  // 111

#define NEG_INF  (-1e30f)

typedef __bf16 bf16x8 __attribute__((ext_vector_type(8)));
typedef float  f32x4  __attribute__((ext_vector_type(4)));

// top-3 insert via med3: 3 independent ops; t0 >= t1 >= t2 invariant.
#define TOP3_INS(v, t0, t1, t2) do {                              \
    float _v = (v);                                               \
    float _n0 = fmaxf(_v, (t0));                                  \
    float _n1 = __builtin_amdgcn_fmed3f(_v, (t0), (t1));          \
    float _n2 = __builtin_amdgcn_fmed3f(_v, (t1), (t2));          \
    (t0) = _n0; (t1) = _n1; (t2) = _n2; } while (0)

// Merge two SORTED triples (u desc, v desc) -> u = top-3 of union. 6 ops.
// Field-validated rounds 9-22 (absmax 0).
#define TRIPLE_MERGE(u0, u1, u2, v0, v1, v2) do {                 \
    float _A = fminf((u0), (v0));                                 \
    float _B = fmaxf((u1), (v1));                                 \
    float _E = fmaxf((u2), (v2));                                 \
    float _m0 = fmaxf((u0), (v0));                                \
    float _m1 = __builtin_amdgcn_fmed3f((u0), (v0), _B);          \
    float _m2 = __builtin_amdgcn_fmed3f(_A, _B, _E);              \
    (u0) = _m0; (u1) = _m1; (u2) = _m2; } while (0)

typedef __attribute__((address_space(1))) const void g_void;
typedef __attribute__((address_space(3))) void l_void;
__device__ __forceinline__ void gload_lds16(const void* g, void* l) {
    __builtin_amdgcn_global_load_lds((g_void*)g, (l_void*)l, 16, 0, 0);
}
#define MFMA16(A, B, C) __builtin_amdgcn_mfma_f32_16x16x32_bf16((A), (B), (C), 0, 0, 0)

// ---------------------------------------------------------------------------
// Kernel 1: L2-normalize all rows (support + anchor) into row-major bf16.
// Support -> sb with per-class row stride PER_CLS_PAD; pad rows zero-filled.
// ---------------------------------------------------------------------------
__global__ __launch_bounds__(256) void norm_rows_kernel(
    const float* __restrict__ anchor, const float* __restrict__ support,
    __bf16* __restrict__ qb, __bf16* __restrict__ sb) {
    int r = blockIdx.x * 256 + threadIdx.x;
    const int total_main = MSUP + NROWS;
    if (r >= total_main) {
        int i = r - total_main;                    // pad-row zero fill
        if (i < CLASSES * NPAD) {
            int cls = i / NPAD, ix = PER_CLS + i % NPAD;
            __bf16* op = sb + ((size_t)cls * PER_CLS_PAD + ix) * C_DIM;
            bf16x8 z = {};
            #pragma unroll
            for (int c0 = 0; c0 < C_DIM; c0 += 8) *(bf16x8*)(op + c0) = z;
        }
        return;
    }
    bool isSup = r < MSUP;
    int rc = isSup ? r : r - MSUP;
    const float* in = isSup ? support : anchor;
    int img = rc / HW, p = rc % HW;
    const float* base = in + (size_t)img * C_DIM * HW + p;
    float q[C_DIM];
    float ss = 0.f;
    #pragma unroll
    for (int c = 0; c < C_DIM; ++c) { q[c] = base[c * HW]; ss += q[c] * q[c]; }
    float sc = rsqrtf(ss);
    __bf16* op;
    if (isSup) {
        int cls = rc / PER_CLS, ix = rc - cls * PER_CLS;
        op = sb + ((size_t)cls * PER_CLS_PAD + ix) * C_DIM;
    } else {
        op = qb + (size_t)rc * C_DIM;
    }
    #pragma unroll
    for (int c0 = 0; c0 < C_DIM; c0 += 8) {
        bf16x8 v;
        #pragma unroll
        for (int j = 0; j < 8; ++j) v[j] = (__bf16)(q[c0 + j] * sc);
        *(bf16x8*)(op + c0) = v;
    }
}

// ---------------------------------------------------------------------------
// SWAPPED-OPERAND GEMM+top3 over one column-quarter (QNT tiles of 32 cols).
// EXACT round-20 champion structure: support tile = MFMA A operand from LDS
// (contiguous 1KB/wave staging + XOR both-sides swizzle, 3 buffers, counted
// vmcnt(1)); queries = B operand register frags. C/D col = QUERY row ->
// 2 chains/lane, 12-shuffle epilogue. Decoupled MFMA cluster / TOP3 stream.
// TAIL: s=1 support row = 2192+kg*4+j, valid iff (j==0)||(kg<3).
// ---------------------------------------------------------------------------
template<int QNT, bool TAIL>
__device__ __forceinline__ void gemm_quarter(
    const char* stage_src, char* smem_base, const char* pB,
    int xoff0, int xoff1, int stage_dst_off, int lane, int kg,
    const bf16x8 q0h0, const bf16x8 q0h1, const bf16x8 q1h0, const bf16x8 q1h1,
    float u0[2], float u1[2], float u2[2]) {

    auto stage = [&](int buf, int tt) {
        gload_lds16(stage_src + tt * TILE_BYTES,
                    smem_base + buf * 4096 + stage_dst_off);
    };
    const f32x4 z = {0.f, 0.f, 0.f, 0.f};
    stage(0, 0);
    stage(1, 1);
    #pragma unroll
    for (int tt = 0; tt < QNT; ++tt) {
        if (tt < QNT - 1) asm volatile("s_waitcnt vmcnt(1)" ::: "memory");
        else              asm volatile("s_waitcnt vmcnt(0)" ::: "memory");
        __builtin_amdgcn_s_barrier();
        if (tt + 2 < QNT) stage((tt + 2) % 3, tt + 2);
        const int buf = tt % 3;
        const bool tail = TAIL && (tt == QNT - 1);
        const char* pb = pB + buf * 4096;
        // support A-frags: s=0 rows (tile rows 0-15), s=1 rows (16-31)
        bf16x8 a0h0 = *(const bf16x8*)(pb + xoff0);
        bf16x8 a0h1 = *(const bf16x8*)(pb + xoff1);
        bf16x8 a1h0 = *(const bf16x8*)(pb + 2048 + xoff0);
        bf16x8 a1h1 = *(const bf16x8*)(pb + 2048 + xoff1);
        f32x4 acc00, acc01, acc10, acc11;   // acc{s}{f}
        __builtin_amdgcn_s_setprio(1);
        acc00 = MFMA16(a0h0, q0h0, z);    acc00 = MFMA16(a0h1, q0h1, acc00);
        acc01 = MFMA16(a0h0, q1h0, z);    acc01 = MFMA16(a0h1, q1h1, acc01);
        acc10 = MFMA16(a1h0, q0h0, z);    acc10 = MFMA16(a1h1, q0h1, acc10);
        acc11 = MFMA16(a1h0, q1h0, z);    acc11 = MFMA16(a1h1, q1h1, acc11);
        __builtin_amdgcn_s_setprio(0);
        if (!tail) {
            #pragma unroll
            for (int j = 0; j < 4; ++j) {
                TOP3_INS(acc00[j], u0[0], u1[0], u2[0]);
                TOP3_INS(acc01[j], u0[1], u1[1], u2[1]);
                TOP3_INS(acc10[j], u0[0], u1[0], u2[0]);
                TOP3_INS(acc11[j], u0[1], u1[1], u2[1]);
            }
        } else {
            // s=0 rows (2176..2191) all valid; s=1 row = 2192+kg*4+j,
            // valid iff kg*4+j < 13  <=>  (j==0) || (kg<3)
            #pragma unroll
            for (int j = 0; j < 4; ++j) {
                TOP3_INS(acc00[j], u0[0], u1[0], u2[0]);
                TOP3_INS(acc01[j], u0[1], u1[1], u2[1]);
                bool validj = (j == 0) || (kg < 3);
                float v0 = validj ? acc10[j] : NEG_INF;
                float v1 = validj ? acc11[j] : NEG_INF;
                TOP3_INS(v0, u0[0], u1[0], u2[0]);
                TOP3_INS(v1, u0[1], u1[1], u2[1]);
            }
        }
    }
}

// ---------------------------------------------------------------------------
// Kernel 2: MFMA GEMM + partial top-3 per (row, class, quarter).
// Grid (111, 20), block 256 = 4 waves; wave owns 32 query rows.
// LDS 12 KB (3 x 4KB); contiguous staging + XOR-swizzled LDS reads (R15).
// A-frag (support, LDS): row = lane&15, k = (lane>>4)*8+[0..7].
// B-frag (query, regs): col = lane&15, same k layout.
// C/D: col(query) = lane&15, row(support) = (lane>>4)*4 + reg.
// part layout: [cls][row][quarter][3] (coalesced merge reads — R22 aux fix).
// ---------------------------------------------------------------------------
__global__ __launch_bounds__(256, 4) void knn_mfma_kernel(
    const __bf16* __restrict__ qb, const __bf16* __restrict__ sb,
    float* __restrict__ part) {
    __shared__ char smem[3][4096];   // 12 KB

    int lane = threadIdx.x & 63;
    int w    = threadIdx.x >> 6;           // 0..3
    int lr   = lane & 15;
    int kg   = lane >> 4;
    int cls  = blockIdx.y >> 2;
    int q    = blockIdx.y & 3;
    int rowbase = blockIdx.x * ROWS_PER_BLK + w * 32;

    // query B-frags for the wave's two 16-row groups (clamped ragged tail)
    int r0 = rowbase + lr;       r0 = r0 < NROWS ? r0 : NROWS - 1;
    int r1 = rowbase + 16 + lr;  r1 = r1 < NROWS ? r1 : NROWS - 1;
    const bf16x8* qr0 = (const bf16x8*)(qb + (size_t)r0 * C_DIM);
    const bf16x8* qr1 = (const bf16x8*)(qb + (size_t)r1 * C_DIM);
    bf16x8 q0h0 = qr0[kg], q0h1 = qr0[4 + kg];
    bf16x8 q1h0 = qr1[kg], q1h1 = qr1[4 + kg];

    float u0[2], u1[2], u2[2];
    #pragma unroll
    for (int f = 0; f < 2; ++f) { u0[f] = NEG_INF; u1[f] = NEG_INF; u2[f] = NEG_INF; }

    // ---- contiguous-stage addressing (validated R15) ----------------------
    int srow = lane >> 3;                       // 0..7 (row within 1KB chunk)
    int sgrn = (lane & 7) ^ (srow & 7);         // XOR-permuted granule
    int srcSwz = srow * 128 + sgrn * 16;        // contiguous 1KB footprint
    const char* qbase = (const char*)sb
        + (size_t)cls * PER_CLS_PAD * ROW_BYTES
        + (size_t)q * TILES_PER_Q * TILE_BYTES;
    const char* stage_src = qbase + w * 1024 + srcSwz;
    // ---- swizzled A-fragment read addressing ------------------------------
    int xoff0 = (((lr & 7) ^ kg) << 4);         // k-half 0
    int xoff1 = xoff0 ^ 0x40;                   // k-half 1 (flip bit 6)
    const char* pB = (const char*)smem + lr * 128;

    if (q == 3)   // tiles 54..68 valid (69..71 all-pad skipped), tail masked
        gemm_quarter<15, true >(stage_src, (char*)smem, pB, xoff0, xoff1,
                                w * 1024, lane, kg,
                                q0h0, q0h1, q1h0, q1h1, u0, u1, u2);
    else
        gemm_quarter<18, false>(stage_src, (char*)smem, pB, xoff0, xoff1,
                                w * 1024, lane, kg,
                                q0h0, q0h1, q1h0, q1h1, u0, u1, u2);

    // Merge top-3 across the 4 kg-lanes per query row (offsets 16, 32);
    // 2 chains x 2 steps x 3 shfl = 12 shuffles/wave.
    #pragma unroll
    for (int f = 0; f < 2; ++f) {
        float a0 = u0[f], a1 = u1[f], a2 = u2[f];
        #pragma unroll
        for (int off = 16; off < 64; off <<= 1) {
            float v0 = __shfl_xor(a0, off, 64);
            float v1 = __shfl_xor(a1, off, 64);
            float v2 = __shfl_xor(a2, off, 64);
            TRIPLE_MERGE(a0, a1, a2, v0, v1, v2);
        }
        int row = rowbase + f * 16 + lr;
        if (kg == 0 && row < NROWS) {
            float* pp = part +
                (((size_t)cls * NROWS + row) * QUARTERS + q) * 3;
            pp[0] = a0; pp[1] = a1; pp[2] = a2;
        }
    }
}

// ---------------------------------------------------------------------------
// Kernel 3: merge quarter partial top-3s, sigmoid, reduce over 441 locations.
// part layout [cls][row][q][3]: lane-adjacent rows are 48B apart -> coalesced.
// ---------------------------------------------------------------------------
__global__ __launch_bounds__(64) void merge_reduce_kernel(
    const float* __restrict__ part, float* __restrict__ out) {
    int bl = blockIdx.x;
    int b = bl / CLASSES;
    int l = bl % CLASSES;
    int lane = threadIdx.x;
    float acc = 0.f;
    for (int p = lane; p < HW; p += 64) {
        int row = b * HW + p;
        const float* pp = part + (((size_t)l * NROWS + row) * QUARTERS) * 3;
        float u0 = pp[0], u1 = pp[1], u2 = pp[2];
        TRIPLE_MERGE(u0, u1, u2, pp[3], pp[4],  pp[5]);
        TRIPLE_MERGE(u0, u1, u2, pp[6], pp[7],  pp[8]);
        TRIPLE_MERGE(u0, u1, u2, pp[9], pp[10], pp[11]);
        acc += 1.f / (1.f + __expf(-u0))
             + 1.f / (1.f + __expf(-u1))
             + 1.f / (1.f + __expf(-u2));
    }
    #pragma unroll
    for (int off = 32; off; off >>= 1) acc += __shfl_xor(acc, off, 64);
    if (lane == 0) out[bl] = acc;
}

// ---------------------------------------------------------------------------
extern "C" void kernel_launch(void* const* d_in, const int* in_sizes, int n_in,
                              void* d_out, int out_size, void* d_ws, size_t ws_size,
                              hipStream_t stream) {
    const float* anchor  = (const float*)d_in[0];
    const float* support = (const float*)d_in[1];
    // d_in[2]=av_num(1), d_in[3]=sav_num(1) -- fixed by setup, ignored.

    // ws: sb bf16[5*2304*64] | qb bf16[NROWS*64] | part f32[5*NROWS*4*3]
    __bf16* sb = (__bf16*)d_ws;
    __bf16* qb = sb + (size_t)CLASSES * PER_CLS_PAD * C_DIM;
    float* part = (float*)(qb + (size_t)NROWS * C_DIM);

    {
        int total = MSUP + NROWS + CLASSES * NPAD;
        dim3 g((total + 255) / 256);
        norm_rows_kernel<<<g, 256, 0, stream>>>(anchor, support, qb, sb);
    }
    {
        dim3 g(NBLK_X, CLASSES * QUARTERS);
        knn_mfma_kernel<<<g, 256, 0, stream>>>(qb, sb, part);
    }
    {
        dim3 gm(B_ANCH * CLASSES);
        merge_reduce_kernel<<<gm, 64, 0, stream>>>(part, (float*)d_out);
    }
}